// Round 2
// baseline (1063.207 us; speedup 1.0000x reference)
//
#include <hip/hip_runtime.h>

#define TPB 256
#define NDMAX 8
#define HREG 8   // supports H up to HREG*TPB = 2048

// One block per (batch, mask_type, channel). Exploits exact sparsity of the
// masked softmax: masked-out positions get attention weight exactly 0.0f
// (expf(-1e30 - max) underflows in fp32), so only selected token positions
// (<= window+1 for the hte mask, ~12 for the desc mask) contribute.
// Single dispatch: every block writes its own out[b][m][c][0..H) slice, so
// no memset and no atomics are needed.
__global__ void mha_agg_kernel(const float* __restrict__ hidden,
                               const int* __restrict__ ids,
                               const float* __restrict__ layer_logits,
                               const float* __restrict__ scorer_w,
                               const int* __restrict__ hte_id_p,
                               const int* __restrict__ d_tok,
                               const int* __restrict__ window_p,
                               float* __restrict__ out,
                               int L, int B, int T, int H, int C, int ND)
{
    const int bid  = blockIdx.x;
    const int c    = bid % C;
    const int m    = (bid / C) & 1;      // 0 = hte window mask, 1 = desc mask
    const int b    = bid / (2 * C);
    const int tid  = threadIdx.x;
    const int wave = tid >> 6;
    const int lane = tid & 63;

    extern __shared__ unsigned char smem[];
    unsigned short* s_sel  = (unsigned short*)smem;                  // T entries
    float*          s_w    = (float*)(smem + ((2 * T + 15) & ~15));  // H floats (scorer row c)
    float*          s_sc   = s_w + H;                                // T floats (scores)
    int*            s_misc = (int*)(s_sc + T);                       // [0]=minpos [1]=count

    if (tid == 0) { s_misc[0] = T; s_misc[1] = 0; }
    for (int h = tid; h < H; h += TPB) s_w[h] = scorer_w[(size_t)c * H + h];
    __syncthreads();

    // ---- build selected-position list for this (b, m) ----
    const int* idrow = ids + (size_t)b * T;
    if (m == 0) {
        const int hte = hte_id_p[0];
        for (int t = tid; t < T; t += TPB)
            if (idrow[t] == hte) atomicMin(&s_misc[0], t);
        __syncthreads();
        if (tid == 0) {
            int pos = s_misc[0]; if (pos >= T) pos = T - 1;   // no hte -> T-1
            int win = window_p[0];
            int hi = pos + win; if (hi > T - 1) hi = T - 1;
            int nn = hi - pos + 1;
            for (int i = 0; i < nn; i++) s_sel[i] = (unsigned short)(pos + i);
            s_misc[1] = nn;
        }
    } else {
        int dt[NDMAX];
        for (int d = 0; d < ND; d++) dt[d] = d_tok[d];
        for (int t = tid; t < T; t += TPB) {
            int v = idrow[t];
            bool hit = false;
            for (int d = 0; d < ND; d++) hit = hit || (v == dt[d]);
            if (hit) { int k = atomicAdd(&s_misc[1], 1); s_sel[k] = (unsigned short)t; }
        }
        __syncthreads();
        if (tid == 0 && s_misc[1] == 0) { s_sel[0] = 0; s_misc[1] = 1; }  // fallback t=0
    }
    __syncthreads();
    const int n = s_misc[1];

    // ---- layer-softmax prep (redundant per thread; L = 12) ----
    float lmx = -3.402823466e38f;
    for (int j = 0; j < L; j++) lmx = fmaxf(lmx, layer_logits[j]);
    float lden = 0.f;
    for (int j = 0; j < L; j++) lden += expf(layer_logits[j] - lmx);

    const int nh = (H + TPB - 1) / TPB;
    float acc[HREG];
    for (int k = 0; k < HREG; k++) acc[k] = 0.f;

    for (int l = 0; l < L; l++) {
        const float lwl = expf(layer_logits[l] - lmx) / lden;
        const float* base = hidden + ((size_t)(l + 1) * B + b) * (size_t)T * H;

        // scores[i] = dot(row_i, w_c); one wave per selected row
        for (int i = wave; i < n; i += TPB / 64) {
            const float* row = base + (size_t)s_sel[i] * H;
            float p = 0.f;
            for (int h = lane; h < H; h += 64) p += row[h] * s_w[h];
            for (int off = 32; off; off >>= 1) p += __shfl_down(p, off);
            if (lane == 0) s_sc[i] = p;
        }
        __syncthreads();

        // softmax stats, redundant per thread (deterministic; n is small)
        float smax = -3.402823466e38f;
        for (int i = 0; i < n; i++) smax = fmaxf(smax, s_sc[i]);
        float ssum = 0.f;
        for (int i = 0; i < n; i++) ssum += expf(s_sc[i] - smax);
        const float scale = lwl / ssum;

        // acc[h] += sum_i attn_i * row_i[h]   (rows L2-hot from the score pass)
        for (int i = 0; i < n; i++) {
            const float wgt = expf(s_sc[i] - smax) * scale;
            const float* row = base + (size_t)s_sel[i] * H;
            for (int k = 0; k < nh; k++) {
                int h = tid + k * TPB;
                if (h < H) acc[k] += wgt * row[h];
            }
        }
        __syncthreads();   // s_sc reused next layer
    }

    float* obase = out + (((size_t)b * 2 + m) * C + c) * (size_t)H;
    for (int k = 0; k < nh; k++) {
        int h = tid + k * TPB;
        if (h < H) obase[h] = acc[k];
    }
}

extern "C" void kernel_launch(void* const* d_in, const int* in_sizes, int n_in,
                              void* d_out, int out_size, void* d_ws, size_t ws_size,
                              hipStream_t stream) {
    const float* hidden = (const float*)d_in[0];   // (L+1, B, T, H) fp32
    const int*   ids    = (const int*)d_in[1];     // (B, T)
    const float* ll     = (const float*)d_in[2];   // (L,)
    const float* sw     = (const float*)d_in[3];   // (C, H)
    const int*   hte    = (const int*)d_in[4];     // scalar
    const int*   dtok   = (const int*)d_in[5];     // (ND,)
    const int*   win    = (const int*)d_in[6];     // scalar
    float*       out    = (float*)d_out;           // (B, 2*C*H)

    const int L  = in_sizes[2];
    const int CH = in_sizes[3];
    const int B  = out_size / (2 * CH);
    const int T  = in_sizes[1] / B;
    const int H  = (int)((long long)in_sizes[0] / ((long long)(L + 1) * in_sizes[1]));
    const int C  = CH / H;
    const int ND = in_sizes[5];

    const size_t smem = (size_t)((2 * T + 15) & ~15)   // sel list (ushort)
                      + (size_t)H * sizeof(float)       // scorer row
                      + (size_t)T * sizeof(float)       // scores
                      + 16;                             // misc
    mha_agg_kernel<<<B * 2 * C, TPB, smem, stream>>>(hidden, ids, ll, sw, hte, dtok, win, out,
                                                     L, B, T, H, C, ND);
}